// Round 14
// baseline (170.609 us; speedup 1.0000x reference)
//
#include <hip/hip_runtime.h>
#include <stdint.h>

// BinaryLinear: out[8192,4096] = x @ W^T + sign(bias); W,b in {-1,+1}.
// Round 14: r13 + surgical one-phase-ahead reads (r12 showed full front-load
// overwhelms regs; this moves only what fits): b1 reads -> P1-tail (0 new
// regs); a1 kk0-half -> P2 into new anew[4] (+16 regs); a1 kk1-half -> P3
// into a[odd] (a0's kk1 regs, dead after P2 MM), consumed only by P3's
// second MFMA octet. STAGEs, barriers, vmcnt(6) ledger identical to r13.

#define M_DIM 8192
#define N_DIM 4096
#define K_DIM 4096
#define NKT   (K_DIM / 128)        // 32 K-tiles of 128 k-elems
#define KROWB ((size_t)K_DIM)      // row bytes of i8 operand = 4096
#define XSCALE 0.04724409448f      // 6/127
#define XINV   21.16666667f        // 127/6

typedef int   i32x4 __attribute__((ext_vector_type(4)));
typedef unsigned int uint_t;

// ---- fused conversion kernel: f32 -> i8 ------------------------------------

static __device__ __forceinline__ int q8(float f) {
    int q = __float2int_rn(f * XINV);
    q = q > 127 ? 127 : q;
    q = q < -127 ? -127 : q;
    return q & 255;
}

// blocks [0, 8192): x (8192*4096 elems, 16/thread); [8192, 12288): w.
__global__ __launch_bounds__(256) void cvt_fused_i8(const float* __restrict__ x,
                                                    const float* __restrict__ wsrc,
                                                    uint_t* __restrict__ xq,
                                                    uint_t* __restrict__ wq) {
    const int bid = blockIdx.x;
    if (bid < 8192) {
        size_t base = ((size_t)bid * 256 + threadIdx.x) * 16;
        uint4 o;
        uint_t* ww = (uint_t*)&o;
#pragma unroll
        for (int g = 0; g < 4; ++g) {
            float4 v = *reinterpret_cast<const float4*>(x + base + g * 4);
            ww[g] = (uint_t)q8(v.x) | ((uint_t)q8(v.y) << 8) |
                    ((uint_t)q8(v.z) << 16) | ((uint_t)q8(v.w) << 24);
        }
        *reinterpret_cast<uint4*>((char*)xq + base) = o;
    } else {
        size_t base = ((size_t)(bid - 8192) * 256 + threadIdx.x) * 16;
        uint4 o;
        uint_t* ww = (uint_t*)&o;
#pragma unroll
        for (int g = 0; g < 4; ++g) {
            float4 v = *reinterpret_cast<const float4*>(wsrc + base + g * 4);
            uint_t b0 = (v.x >= 0.f) ? 0x01u : 0xFFu;
            uint_t b1 = (v.y >= 0.f) ? 0x01u : 0xFFu;
            uint_t b2 = (v.z >= 0.f) ? 0x01u : 0xFFu;
            uint_t b3 = (v.w >= 0.f) ? 0x01u : 0xFFu;
            ww[g] = b0 | (b1 << 8) | (b2 << 16) | (b3 << 24);
        }
        *reinterpret_cast<uint4*>((char*)wq + base) = o;
    }
}

// ---- GEMM ------------------------------------------------------------------
// LDS: buf b at b*65536; A region +0 (32KB = 256 rows x 128B), B at +32768.
// Half h = 128 rows = 16KB at h*16384. Swizzle involution within region:
// P = L ^ (((L>>7)&7)<<4).

static __device__ __forceinline__ void gload_lds16(const void* g, void* s) {
    __builtin_amdgcn_global_load_lds(
        (const __attribute__((address_space(1))) void*)(g),
        (__attribute__((address_space(3))) void*)(s),
        16, 0, 0);
}

#define STAGE_A(bufbase, h, kt) do {                                        \
    char* _d = (bufbase) + (h)*16384 + w*1024;                              \
    gload_lds16(srcA0 + (size_t)(h)*524288 + (size_t)(kt)*128, _d);         \
    gload_lds16(srcA1 + (size_t)(h)*524288 + (size_t)(kt)*128, _d + 8192);  \
} while (0)

#define STAGE_B(bufbase, h, kt) do {                                        \
    char* _d = (bufbase) + 32768 + (h)*16384 + w*1024;                      \
    gload_lds16(srcB0 + (size_t)(h)*524288 + (size_t)(kt)*128, _d);         \
    gload_lds16(srcB1 + (size_t)(h)*524288 + (size_t)(kt)*128, _d + 8192);  \
} while (0)

// Per-kk fragment reads: lane l reads 16B at logical col kk*64 + kh*16 of
// one 128B row; physical col = c ^ ((row&7)<<4).
#define LDA_K(base, Mh, kk, areg) do {                                      \
    const int _sx = (kk) ? sxk1 : sxk0;                                     \
    _Pragma("unroll") for (int m = 0; m < 4; ++m)                           \
        areg[m*2+(kk)] = *(const i32x4*)((base) + pbA + (Mh)*16384          \
                                         + m*2048 + _sx);                   \
} while (0)

#define LDB_K(base, Nh, kk, breg) do {                                      \
    const int _sx = (kk) ? sxk1 : sxk0;                                     \
    _Pragma("unroll") for (int n = 0; n < 2; ++n)                           \
        breg[n*2+(kk)] = *(const i32x4*)((base) + pbB + (Nh)*16384          \
                                         + n*2048 + _sx);                   \
} while (0)

// A-h1 kk0 half into anew[4] (issued one phase early, P2).
#define LDA1K0(base, anreg) do {                                            \
    _Pragma("unroll") for (int m = 0; m < 4; ++m)                           \
        anreg[m] = *(const i32x4*)((base) + pbA + 16384 + m*2048 + sxk0);   \
} while (0)

// A-h1 kk1 half into a[odd] (a0's kk1 slots, dead after P2's MM).
#define LDA1K1(base, areg) do {                                             \
    _Pragma("unroll") for (int m = 0; m < 4; ++m)                           \
        areg[m*2+1] = *(const i32x4*)((base) + pbA + 16384 + m*2048 + sxk1);\
} while (0)

// 16 MFMA, standard frags (a holds both kk in a[m*2+kk]).
#define MM16(areg, breg, accq) do {                                         \
    __builtin_amdgcn_s_setprio(1);                                          \
    _Pragma("unroll") for (int kk = 0; kk < 2; ++kk)                        \
    _Pragma("unroll") for (int m = 0; m < 4; ++m)                           \
    _Pragma("unroll") for (int n = 0; n < 2; ++n)                           \
        accq[m][n] = __builtin_amdgcn_mfma_i32_16x16x64_i8(                 \
            areg[m*2+kk], breg[n*2+kk], accq[m][n], 0, 0, 0);               \
    __builtin_amdgcn_s_setprio(0);                                          \
} while (0)

// 16 MFMA, hybrid frags: kk0 from anew[m], kk1 from a[m*2+1].
// kk0 octet first: its operands (anew, read in P2) are ready; the kk1
// octet's reads (issued this phase) drain under the kk0 MFMAs.
#define MM16H(anreg, areg, breg, accq) do {                                 \
    __builtin_amdgcn_s_setprio(1);                                          \
    _Pragma("unroll") for (int m = 0; m < 4; ++m)                           \
    _Pragma("unroll") for (int n = 0; n < 2; ++n)                           \
        accq[m][n] = __builtin_amdgcn_mfma_i32_16x16x64_i8(                 \
            anreg[m], breg[n*2+0], accq[m][n], 0, 0, 0);                    \
    _Pragma("unroll") for (int m = 0; m < 4; ++m)                           \
    _Pragma("unroll") for (int n = 0; n < 2; ++n)                           \
        accq[m][n] = __builtin_amdgcn_mfma_i32_16x16x64_i8(                 \
            areg[m*2+1], breg[n*2+1], accq[m][n], 0, 0, 0);                 \
    __builtin_amdgcn_s_setprio(0);                                          \
} while (0)

#define BAR() __builtin_amdgcn_s_barrier()

// One K-tile = 4 phases, 4 barriers (r13), reads one phase ahead.
#define TILE4(curb, othb, kt, g, gb) do {                                   \
    char* Ab = (curb);                                                      \
    /* P1: (Mh0,Nh0); reads a0,b0 (for P1) then b1 (for P2) */              \
    LDA_K(Ab, 0, 0, a); LDB_K(Ab, 0, 0, b0);                                \
    LDA_K(Ab, 0, 1, a); LDB_K(Ab, 0, 1, b0);                                \
    LDB_K(Ab, 1, 0, b1); LDB_K(Ab, 1, 1, b1);                               \
    if (gb) STAGE_B((othb), 1, (kt) + 1);                                   \
    MM16(a, b0, acc[0][0]);                                                 \
    BAR();   /* a0,b0 (and b1) reads retired on all waves */                \
    /* P2: (Mh0,Nh1); read a1-kk0 early into anew */                        \
    LDA1K0(Ab, anew);                                                       \
    if (g) STAGE_A((curb), 0, (kt) + 2);                                    \
    MM16(a, b1, acc[0][1]);                                                 \
    BAR();                                                                  \
    /* P3: (Mh1,Nh1); read a1-kk1 into a[odd]; kk0 MFMAs cover the drain */ \
    LDA1K1(Ab, a);                                                          \
    if (g) STAGE_B((curb), 0, (kt) + 2);                                    \
    MM16H(anew, a, b1, acc[1][1]);                                          \
    BAR();   /* all A-h1 reads retired on all waves */                      \
    /* P4: (Mh1,Nh0) — read-free */                                         \
    if (g) STAGE_A((curb), 1, (kt) + 2);                                    \
    MM16H(anew, a, b0, acc[1][0]);                                          \
} while (0)

__global__ __launch_bounds__(512, 2)
void bgemm_i8_kernel(const char* __restrict__ Aq, const char* __restrict__ Bq,
                     const float* __restrict__ bias, float* __restrict__ C) {
    __shared__ char lds[131072];

    const int t = threadIdx.x;
    const int w = t >> 6;          // wave 0..7
    const int l = t & 63;
    const int wr = w >> 2;         // 0..1 (M)
    const int wc = w & 3;          // 0..3 (N)

    // XCD swizzle: 512 blocks, 512 % 8 == 0 -> bijective
    const int bid = blockIdx.x;
    const int wg  = (bid & 7) * 64 + (bid >> 3);
    const int tn  = wg & 15;       // N tiles: 4096/256 = 16
    const int tm  = wg >> 4;       // M tiles: 8192/256 = 32

    // ---- staging: thread t, call j covers physical bytes [(j*512+t)*16,+16)
    // of a 16KB half-tile; invert swizzle for the global source.
    int srow[2], skb[2];
#pragma unroll
    for (int j = 0; j < 2; ++j) {
        int p = (j * 512 + t) * 16;
        int L = p ^ (((p >> 7) & 7) << 4);
        srow[j] = L >> 7;          // 0..127
        skb[j]  = L & 127;         // byte col within 128B row
    }
    const char* srcA0 = Aq + ((size_t)(tm * 256) + srow[0]) * KROWB + skb[0];
    const char* srcA1 = Aq + ((size_t)(tm * 256) + srow[1]) * KROWB + skb[1];
    const char* srcB0 = Bq + ((size_t)(tn * 256) + srow[0]) * KROWB + skb[0];
    const char* srcB1 = Bq + ((size_t)(tn * 256) + srow[1]) * KROWB + skb[1];

    // ---- fragment addressing: logical col c = kk*64 + kh*16 bytes;
    // physical = c ^ ((row&7)<<4), row&7 == l&7 (all row bases mult of 8).
    const int lr = l & 15;
    const int kh = l >> 4;
    const int x7 = (l & 7) << 4;
    const int sxk0 = (kh * 16) ^ x7;
    const int sxk1 = (64 + kh * 16) ^ x7;
    const int pbA = (wr * 64 + lr) * 128;
    const int pbB = 32768 + (wc * 32 + lr) * 128;

    char* const buf0 = lds;
    char* const buf1 = lds + 65536;

    // ---- prologue: tile0 all 4 halves -> buf0; tile1 A0,B0,A1 -> buf1
    STAGE_A(buf0, 0, 0); STAGE_B(buf0, 0, 0); STAGE_A(buf0, 1, 0); STAGE_B(buf0, 1, 0);
    STAGE_A(buf1, 0, 1); STAGE_B(buf1, 0, 1); STAGE_A(buf1, 1, 1);
    asm volatile("s_waitcnt vmcnt(6)" ::: "memory");
    BAR();

    i32x4 acc[2][2][4][2] = {};
    i32x4 a[8], anew[4], b0[4], b1[4];

#pragma unroll 1
    for (int kt = 0; kt < NKT; kt += 2) {
        const bool g = (kt < NKT - 2);   // stage-(+2) guard, uniform

        // ---- even tile kt: buf0 current (kt+1 <= NKT-1 so gb always true)
        TILE4(buf0, buf1, kt, g, true);
        if (g)  asm volatile("s_waitcnt vmcnt(6)" ::: "memory");
        else    asm volatile("s_waitcnt vmcnt(0)" ::: "memory");
        BAR();

        // ---- odd tile kt+1: buf1 current; gb = (kt+2 < NKT) == g
        TILE4(buf1, buf0, kt + 1, g, g);
        if (g) {
            asm volatile("s_waitcnt vmcnt(6)" ::: "memory");
            BAR();
        }
    }

    // ---- epilogue: C/D 16x16 layout col=lane&15, row=(lane>>4)*4+reg;
    // out = scale * acc + sign(bias)
    const int r0 = tm * 256 + wr * 64 + kh * 4;
    const int c0 = tn * 256 + wc * 32 + lr;
#pragma unroll
    for (int Mh = 0; Mh < 2; ++Mh)
#pragma unroll
    for (int Nh = 0; Nh < 2; ++Nh)
#pragma unroll
    for (int n = 0; n < 2; ++n) {
        const int col = c0 + Nh * 128 + n * 16;
        const float bs = (bias[col] >= 0.f) ? 1.f : -1.f;
#pragma unroll
        for (int m = 0; m < 4; ++m)
#pragma unroll
        for (int j = 0; j < 4; ++j) {
            const int row = r0 + Mh * 128 + m * 16 + j;
            C[(size_t)row * N_DIM + col] =
                (float)acc[Mh][Nh][m][n][j] * XSCALE + bs;
        }
    }
}

extern "C" void kernel_launch(void* const* d_in, const int* in_sizes, int n_in,
                              void* d_out, int out_size, void* d_ws, size_t ws_size,
                              hipStream_t stream) {
    const float* x    = (const float*)d_in[0];
    const float* wgt  = (const float*)d_in[1];
    const float* bias = (const float*)d_in[2];
    float* out = (float*)d_out;

    // workspace: xq = 8192*4096 i8 (32MB), wq = 4096*4096 i8 (16MB)
    char* xq = (char*)d_ws;
    char* wq = xq + (size_t)M_DIM * K_DIM;

    cvt_fused_i8<<<12288, 256, 0, stream>>>(x, wgt, (uint_t*)xq, (uint_t*)wq);

    dim3 grid((M_DIM / 256) * (N_DIM / 256));             // 32*16 = 512
    bgemm_i8_kernel<<<grid, 512, 0, stream>>>(xq, wq, bias, out);
}

// Round 15
// 168.436 us; speedup vs baseline: 1.0129x; 1.0129x over previous
//
#include <hip/hip_runtime.h>
#include <stdint.h>

// BinaryLinear: out[8192,4096] = x @ W^T + sign(bias); W,b in {-1,+1}.
// Round 15: r13 (best: 129us GEMM / 169.6us total) with ONE change —
// BAR after P2 removed (4 -> 3 barriers per K-tile). Liveness re-proof:
// P3's STAGE_B(h0) needs b0-reads retired -> BAR1; P4's STAGE_A(h1) needs
// a1-reads retired -> BAR3; next-tile STAGE_B(h1) -> BAR3+boundary BAR;
// all fast/slow wave interleavings touch disjoint LDS regions. vmcnt(6)
// ledger identical to r10/r13. Read placement = r13 exactly (r7/r12/r14
// all confirmed per-phase placement is optimal).

#define M_DIM 8192
#define N_DIM 4096
#define K_DIM 4096
#define NKT   (K_DIM / 128)        // 32 K-tiles of 128 k-elems
#define KROWB ((size_t)K_DIM)      // row bytes of i8 operand = 4096
#define XSCALE 0.04724409448f      // 6/127
#define XINV   21.16666667f        // 127/6

typedef int   i32x4 __attribute__((ext_vector_type(4)));
typedef unsigned int uint_t;

// ---- fused conversion kernel: f32 -> i8 ------------------------------------

static __device__ __forceinline__ int q8(float f) {
    int q = __float2int_rn(f * XINV);
    q = q > 127 ? 127 : q;
    q = q < -127 ? -127 : q;
    return q & 255;
}

// blocks [0, 8192): x (8192*4096 elems, 16/thread); [8192, 12288): w.
__global__ __launch_bounds__(256) void cvt_fused_i8(const float* __restrict__ x,
                                                    const float* __restrict__ wsrc,
                                                    uint_t* __restrict__ xq,
                                                    uint_t* __restrict__ wq) {
    const int bid = blockIdx.x;
    if (bid < 8192) {
        size_t base = ((size_t)bid * 256 + threadIdx.x) * 16;
        uint4 o;
        uint_t* ww = (uint_t*)&o;
#pragma unroll
        for (int g = 0; g < 4; ++g) {
            float4 v = *reinterpret_cast<const float4*>(x + base + g * 4);
            ww[g] = (uint_t)q8(v.x) | ((uint_t)q8(v.y) << 8) |
                    ((uint_t)q8(v.z) << 16) | ((uint_t)q8(v.w) << 24);
        }
        *reinterpret_cast<uint4*>((char*)xq + base) = o;
    } else {
        size_t base = ((size_t)(bid - 8192) * 256 + threadIdx.x) * 16;
        uint4 o;
        uint_t* ww = (uint_t*)&o;
#pragma unroll
        for (int g = 0; g < 4; ++g) {
            float4 v = *reinterpret_cast<const float4*>(wsrc + base + g * 4);
            uint_t b0 = (v.x >= 0.f) ? 0x01u : 0xFFu;
            uint_t b1 = (v.y >= 0.f) ? 0x01u : 0xFFu;
            uint_t b2 = (v.z >= 0.f) ? 0x01u : 0xFFu;
            uint_t b3 = (v.w >= 0.f) ? 0x01u : 0xFFu;
            ww[g] = b0 | (b1 << 8) | (b2 << 16) | (b3 << 24);
        }
        *reinterpret_cast<uint4*>((char*)wq + base) = o;
    }
}

// ---- GEMM ------------------------------------------------------------------
// LDS: buf b at b*65536; A region +0 (32KB = 256 rows x 128B), B at +32768.
// Half h = 128 rows = 16KB at h*16384. Swizzle involution within region:
// P = L ^ (((L>>7)&7)<<4).

static __device__ __forceinline__ void gload_lds16(const void* g, void* s) {
    __builtin_amdgcn_global_load_lds(
        (const __attribute__((address_space(1))) void*)(g),
        (__attribute__((address_space(3))) void*)(s),
        16, 0, 0);
}

#define STAGE_A(bufbase, h, kt) do {                                        \
    char* _d = (bufbase) + (h)*16384 + w*1024;                              \
    gload_lds16(srcA0 + (size_t)(h)*524288 + (size_t)(kt)*128, _d);         \
    gload_lds16(srcA1 + (size_t)(h)*524288 + (size_t)(kt)*128, _d + 8192);  \
} while (0)

#define STAGE_B(bufbase, h, kt) do {                                        \
    char* _d = (bufbase) + 32768 + (h)*16384 + w*1024;                      \
    gload_lds16(srcB0 + (size_t)(h)*524288 + (size_t)(kt)*128, _d);         \
    gload_lds16(srcB1 + (size_t)(h)*524288 + (size_t)(kt)*128, _d + 8192);  \
} while (0)

// Per-kk fragment reads: lane l reads 16B at logical col kk*64 + kh*16 of
// one 128B row; physical col = c ^ ((row&7)<<4).
#define LDA_K(base, Mh, kk, areg) do {                                      \
    const int _sx = (kk) ? sxk1 : sxk0;                                     \
    _Pragma("unroll") for (int m = 0; m < 4; ++m)                           \
        areg[m*2+(kk)] = *(const i32x4*)((base) + pbA + (Mh)*16384          \
                                         + m*2048 + _sx);                   \
} while (0)

#define LDB_K(base, Nh, kk, breg) do {                                      \
    const int _sx = (kk) ? sxk1 : sxk0;                                     \
    _Pragma("unroll") for (int n = 0; n < 2; ++n)                           \
        breg[n*2+(kk)] = *(const i32x4*)((base) + pbB + (Nh)*16384          \
                                         + n*2048 + _sx);                   \
} while (0)

// 16 MFMA per phase via builtin; kk-outer -> 8 independent ops between
// accumulator reuses.
#define MM16(areg, breg, accq) do {                                         \
    __builtin_amdgcn_s_setprio(1);                                          \
    _Pragma("unroll") for (int kk = 0; kk < 2; ++kk)                        \
    _Pragma("unroll") for (int m = 0; m < 4; ++m)                           \
    _Pragma("unroll") for (int n = 0; n < 2; ++n)                           \
        accq[m][n] = __builtin_amdgcn_mfma_i32_16x16x64_i8(                 \
            areg[m*2+kk], breg[n*2+kk], accq[m][n], 0, 0, 0);               \
    __builtin_amdgcn_s_setprio(0);                                          \
} while (0)

#define BAR() __builtin_amdgcn_s_barrier()

// One K-tile = 4 phases, 3 barriers (BAR1 post-P1, BAR3 post-P3, boundary).
#define TILE4(curb, othb, kt, g, gb) do {                                   \
    char* Ab = (curb);                                                      \
    /* P1: (Mh0,Nh0) */                                                     \
    LDA_K(Ab, 0, 0, a); LDB_K(Ab, 0, 0, b0);                                \
    LDA_K(Ab, 0, 1, a); LDB_K(Ab, 0, 1, b0);                                \
    if (gb) STAGE_B((othb), 1, (kt) + 1);                                   \
    MM16(a, b0, acc[0][0]);                                                 \
    BAR();   /* BAR1: a(h0), b0 reads retired on all waves */               \
    /* P2: (Mh0,Nh1) — no trailing barrier */                               \
    LDB_K(Ab, 1, 0, b1); LDB_K(Ab, 1, 1, b1);                               \
    if (g) STAGE_A((curb), 0, (kt) + 2);                                    \
    MM16(a, b1, acc[0][1]);                                                 \
    /* P3: (Mh1,Nh1) */                                                     \
    LDA_K(Ab, 1, 0, a); LDA_K(Ab, 1, 1, a);                                 \
    if (g) STAGE_B((curb), 0, (kt) + 2);                                    \
    MM16(a, b1, acc[1][1]);                                                 \
    BAR();   /* BAR3: a(h1), b1 reads retired on all waves */               \
    /* P4: (Mh1,Nh0) — regs from P3/P1, no reads */                         \
    if (g) STAGE_A((curb), 1, (kt) + 2);                                    \
    MM16(a, b0, acc[1][0]);                                                 \
} while (0)

__global__ __launch_bounds__(512, 2)
void bgemm_i8_kernel(const char* __restrict__ Aq, const char* __restrict__ Bq,
                     const float* __restrict__ bias, float* __restrict__ C) {
    __shared__ char lds[131072];

    const int t = threadIdx.x;
    const int w = t >> 6;          // wave 0..7
    const int l = t & 63;
    const int wr = w >> 2;         // 0..1 (M)
    const int wc = w & 3;          // 0..3 (N)

    // XCD swizzle: 512 blocks, 512 % 8 == 0 -> bijective
    const int bid = blockIdx.x;
    const int wg  = (bid & 7) * 64 + (bid >> 3);
    const int tn  = wg & 15;       // N tiles: 4096/256 = 16
    const int tm  = wg >> 4;       // M tiles: 8192/256 = 32

    // ---- staging: thread t, call j covers physical bytes [(j*512+t)*16,+16)
    // of a 16KB half-tile; invert swizzle for the global source.
    int srow[2], skb[2];
#pragma unroll
    for (int j = 0; j < 2; ++j) {
        int p = (j * 512 + t) * 16;
        int L = p ^ (((p >> 7) & 7) << 4);
        srow[j] = L >> 7;          // 0..127
        skb[j]  = L & 127;         // byte col within 128B row
    }
    const char* srcA0 = Aq + ((size_t)(tm * 256) + srow[0]) * KROWB + skb[0];
    const char* srcA1 = Aq + ((size_t)(tm * 256) + srow[1]) * KROWB + skb[1];
    const char* srcB0 = Bq + ((size_t)(tn * 256) + srow[0]) * KROWB + skb[0];
    const char* srcB1 = Bq + ((size_t)(tn * 256) + srow[1]) * KROWB + skb[1];

    // ---- fragment addressing: logical col c = kk*64 + kh*16 bytes;
    // physical = c ^ ((row&7)<<4), row&7 == l&7 (all row bases mult of 8).
    const int lr = l & 15;
    const int kh = l >> 4;
    const int x7 = (l & 7) << 4;
    const int sxk0 = (kh * 16) ^ x7;
    const int sxk1 = (64 + kh * 16) ^ x7;
    const int pbA = (wr * 64 + lr) * 128;
    const int pbB = 32768 + (wc * 32 + lr) * 128;

    char* const buf0 = lds;
    char* const buf1 = lds + 65536;

    // ---- prologue: tile0 all 4 halves -> buf0; tile1 A0,B0,A1 -> buf1
    STAGE_A(buf0, 0, 0); STAGE_B(buf0, 0, 0); STAGE_A(buf0, 1, 0); STAGE_B(buf0, 1, 0);
    STAGE_A(buf1, 0, 1); STAGE_B(buf1, 0, 1); STAGE_A(buf1, 1, 1);
    asm volatile("s_waitcnt vmcnt(6)" ::: "memory");
    BAR();

    i32x4 acc[2][2][4][2] = {};
    i32x4 a[8], b0[4], b1[4];

#pragma unroll 1
    for (int kt = 0; kt < NKT; kt += 2) {
        const bool g = (kt < NKT - 2);   // stage-(+2) guard, uniform

        // ---- even tile kt: buf0 current (kt+1 <= NKT-1 so gb always true)
        TILE4(buf0, buf1, kt, g, true);
        if (g)  asm volatile("s_waitcnt vmcnt(6)" ::: "memory");
        else    asm volatile("s_waitcnt vmcnt(0)" ::: "memory");
        BAR();

        // ---- odd tile kt+1: buf1 current; gb = (kt+2 < NKT) == g
        TILE4(buf1, buf0, kt + 1, g, g);
        if (g) {
            asm volatile("s_waitcnt vmcnt(6)" ::: "memory");
            BAR();
        }
    }

    // ---- epilogue: C/D 16x16 layout col=lane&15, row=(lane>>4)*4+reg;
    // out = scale * acc + sign(bias)
    const int r0 = tm * 256 + wr * 64 + kh * 4;
    const int c0 = tn * 256 + wc * 32 + lr;
#pragma unroll
    for (int Mh = 0; Mh < 2; ++Mh)
#pragma unroll
    for (int Nh = 0; Nh < 2; ++Nh)
#pragma unroll
    for (int n = 0; n < 2; ++n) {
        const int col = c0 + Nh * 128 + n * 16;
        const float bs = (bias[col] >= 0.f) ? 1.f : -1.f;
#pragma unroll
        for (int m = 0; m < 4; ++m)
#pragma unroll
        for (int j = 0; j < 4; ++j) {
            const int row = r0 + Mh * 128 + m * 16 + j;
            C[(size_t)row * N_DIM + col] =
                (float)acc[Mh][Nh][m][n][j] * XSCALE + bs;
        }
    }
}

extern "C" void kernel_launch(void* const* d_in, const int* in_sizes, int n_in,
                              void* d_out, int out_size, void* d_ws, size_t ws_size,
                              hipStream_t stream) {
    const float* x    = (const float*)d_in[0];
    const float* wgt  = (const float*)d_in[1];
    const float* bias = (const float*)d_in[2];
    float* out = (float*)d_out;

    // workspace: xq = 8192*4096 i8 (32MB), wq = 4096*4096 i8 (16MB)
    char* xq = (char*)d_ws;
    char* wq = xq + (size_t)M_DIM * K_DIM;

    cvt_fused_i8<<<12288, 256, 0, stream>>>(x, wgt, (uint_t*)xq, (uint_t*)wq);

    dim3 grid((M_DIM / 256) * (N_DIM / 256));             // 32*16 = 512
    bgemm_i8_kernel<<<grid, 512, 0, stream>>>(xq, wq, bias, out);
}